// Round 8
// baseline (169.989 us; speedup 1.0000x reference)
//
#include <hip/hip_runtime.h>
#include <cstdint>

#define NNODES 100000
#define NEDGES 1200000
#define INF 64
#define OUTF 32
#define PB 128                                    // nodes per bucket
#define NBUCK ((NNODES + PB - 1) / PB)            // 782; bucket b = dst >> 7
#define PCAP 2048                                 // slots/bucket (mean 1536, sd 39 -> +13 sigma)
#define BIN_EPT 16
#define BIN_THREADS (NEDGES / BIN_EPT)            // 75000
#define BIN_BLOCKS ((BIN_THREADS + 255) / 256)    // 293
#define PROJ_NPB 16
#define PROJ_BLOCKS (NNODES / PROJ_NPB)           // 6250 (exact)
#define CUR_PAD 16                                // 64B-padded global cursors

// ---- cursor init: gcur[b] = b*PCAP ----
__global__ __launch_bounds__(256) void k_initcur(int* __restrict__ gcur) {
    int i = blockIdx.x * 256 + threadIdx.x;
    if (i < NBUCK) gcur[i * CUR_PAD] = i * PCAP;
}

// ---- fused: blocks [0,BIN_BLOCKS) bin edges; rest project h0 = X@W^T ----
// Projection is norm-independent (unscaled h0); hop1 applies norm[src].
__global__ __launch_bounds__(256) void k_binproj(const int4* __restrict__ src4,
                                                 const int4* __restrict__ dst4,
                                                 int* __restrict__ gcur,
                                                 unsigned* __restrict__ packed,
                                                 const float4* __restrict__ feat4,
                                                 const float4* __restrict__ W4,
                                                 float2* __restrict__ h0_2) {
    __shared__ __align__(16) char smem[12480];
    int tid = threadIdx.x;
    if (blockIdx.x < BIN_BLOCKS) {
        int* cnt = (int*)smem;
        int* base = cnt + NBUCK;
        for (int i = tid; i < NBUCK; i += 256) cnt[i] = 0;
        __syncthreads();
        int gid = blockIdx.x * 256 + tid;
        bool act = gid < BIN_THREADS;
        int4 s4[4], d4[4];
        if (act) {
#pragma unroll
            for (int k = 0; k < 4; ++k) {
                s4[k] = src4[(size_t)gid * 4 + k];
                d4[k] = dst4[(size_t)gid * 4 + k];
                atomicAdd(&cnt[d4[k].x >> 7], 1);
                atomicAdd(&cnt[d4[k].y >> 7], 1);
                atomicAdd(&cnt[d4[k].z >> 7], 1);
                atomicAdd(&cnt[d4[k].w >> 7], 1);
            }
        }
        __syncthreads();
        for (int i = tid; i < NBUCK; i += 256) {
            int c = cnt[i];
            base[i] = c ? atomicAdd(&gcur[i * CUR_PAD], c) : 0;
            cnt[i] = 0;
        }
        __syncthreads();
        if (act) {
#pragma unroll
            for (int k = 0; k < 4; ++k) {
                int ss[4] = {s4[k].x, s4[k].y, s4[k].z, s4[k].w};
                int dd[4] = {d4[k].x, d4[k].y, d4[k].z, d4[k].w};
#pragma unroll
                for (int j = 0; j < 4; ++j) {
                    int b = dd[j] >> 7;
                    int rel = atomicAdd(&cnt[b], 1);
                    packed[base[b] + rel] =
                        ((unsigned)(dd[j] & (PB - 1)) << 17) | (unsigned)ss[j];
                }
            }
        }
    } else {
        float (*Ws)[INF + 1] = (float (*)[INF + 1])smem;                 // [32][65]
        float (*Fs)[INF + 1] = (float (*)[INF + 1])(smem + 8320);       // [16][65]
        int node0 = (blockIdx.x - BIN_BLOCKS) * PROJ_NPB;
        for (int i = tid; i < 512; i += 256) {
            float4 w = W4[i];
            int f = i * 4, of = f >> 6, k = f & 63;
            Ws[of][k] = w.x; Ws[of][k + 1] = w.y;
            Ws[of][k + 2] = w.z; Ws[of][k + 3] = w.w;
        }
        {
            int n = node0 + (tid >> 4), q = tid & 15;
            float4 v = feat4[(size_t)n * 16 + q];
            int c = q * 4;
            Fs[tid >> 4][c] = v.x; Fs[tid >> 4][c + 1] = v.y;
            Fs[tid >> 4][c + 2] = v.z; Fs[tid >> 4][c + 3] = v.w;
        }
        __syncthreads();
        int ln = tid >> 4, n = node0 + ln;
        int of0 = (tid & 15) * 2;
        float a0 = 0.0f, a1 = 0.0f;
#pragma unroll
        for (int k = 0; k < INF; ++k) {
            float f = Fs[ln][k];
            a0 += f * Ws[of0][k];
            a1 += f * Ws[of0 + 1][k];
        }
        h0_2[(size_t)n * 16 + (tid & 15)] = make_float2(a0, a1);
    }
}

// ---- per bucket: degree, norm, degree-sorted entries, LDS scatter, col ----
// entries[slot] = {row_start, node | deg<<17}; slots degree-grouped so gather
// waves (8 consecutive slots) process similar-degree nodes (less divergence).
__global__ __launch_bounds__(256) void k_place(const unsigned* __restrict__ packed,
                                               const int* __restrict__ gcur,
                                               int* __restrict__ col,
                                               int2* __restrict__ entries,
                                               float* __restrict__ norm) {
    __shared__ unsigned sin_[PCAP];
    __shared__ int stage[PCAP];
    __shared__ int deg[PB];
    __shared__ int rs[PB];
    __shared__ int cur[PB];
    __shared__ int hist[64];
    __shared__ int hs[64];
    int b = blockIdx.x, tid = threadIdx.x;
    int node0 = b * PB;
    int nn = (NNODES - node0 < PB) ? (NNODES - node0) : PB;
    int ebase = b * PCAP;
    int nedge = gcur[b * CUR_PAD] - ebase;
    if (tid < PB) deg[tid] = 0;
    if (tid < 64) hist[tid] = 0;
    __syncthreads();
    for (int i = tid; i < nedge; i += 256) {
        unsigned pk = packed[ebase + i];
        sin_[i] = pk;
        atomicAdd(&deg[pk >> 17], 1);
    }
    __syncthreads();
    int d = 0;
    if (tid < PB) {
        d = deg[tid];
        rs[tid] = d;
    }
    __syncthreads();
    for (int st = 1; st < PB; st <<= 1) {
        int add = (tid < PB && tid >= st) ? rs[tid - st] : 0;
        __syncthreads();
        if (tid < PB) rs[tid] += add;
        __syncthreads();
    }
    int myoff = (tid < PB) ? rs[tid] - d : 0;  // exclusive scan within bucket
    int bin = d < 63 ? d : 63;
    if (tid < nn) atomicAdd(&hist[bin], 1);
    __syncthreads();
    if (tid < 64) hs[tid] = hist[tid];
    __syncthreads();
    for (int st = 1; st < 64; st <<= 1) {
        int add = (tid < 64 && tid >= st) ? hs[tid - st] : 0;
        __syncthreads();
        if (tid < 64) hs[tid] += add;
        __syncthreads();
    }
    if (tid < 64) hist[tid] = hs[tid] - hist[tid];  // exclusive bases -> cursors
    __syncthreads();
    if (tid < nn) {
        int slot = atomicAdd(&hist[bin], 1);
        entries[node0 + slot] = make_int2(ebase + myoff, (node0 + tid) | (d << 17));
        norm[node0 + tid] = rsqrtf(d < 1 ? 1.0f : (float)d);
    } else if (tid < PB) {
        entries[node0 + tid] = make_int2(0, 0x1FFFF);  // pad: node id >= NNODES
    }
    if (tid < PB) cur[tid] = myoff;
    __syncthreads();
    for (int i = tid; i < nedge; i += 256) {
        unsigned pk = sin_[i];
        int rel = atomicAdd(&cur[pk >> 17], 1);
        stage[rel] = (int)(pk & 0x1FFFFu);
    }
    __syncthreads();
    for (int i = tid; i < nedge; i += 256) col[ebase + i] = stage[i];
}

// ---- one hop: uout[d] = w(d) * sum_e (FIRST? norm[s]:1)*uin[col[e]] (+bias)
// w = norm^2 (mid) or norm (last). 8 lanes/node, float4 each, 8-deep MLP.
template <bool FIRST, bool LAST>
__global__ __launch_bounds__(256) void k_gather(const float4* __restrict__ uin,
                                                float4* __restrict__ uout,
                                                const int2* __restrict__ entries,
                                                const int* __restrict__ col,
                                                const float* __restrict__ norm,
                                                const float4* __restrict__ bias4) {
    int t = blockIdx.x * 256 + threadIdx.x;
    int slot = t >> 3;
    if (slot >= NBUCK * PB) return;
    int lane = t & 7;
    int2 en = entries[slot];
    int node = en.y & 0x1FFFF;
    if (node >= NNODES) return;
    int e = en.x, re = e + (en.y >> 17);
    float4 acc = make_float4(0.f, 0.f, 0.f, 0.f);
    for (; e + 7 < re; e += 8) {
        int s0 = col[e],     s1 = col[e + 1], s2 = col[e + 2], s3 = col[e + 3];
        int s4 = col[e + 4], s5 = col[e + 5], s6 = col[e + 6], s7 = col[e + 7];
        float4 a0 = uin[(size_t)s0 * 8 + lane];
        float4 a1 = uin[(size_t)s1 * 8 + lane];
        float4 a2 = uin[(size_t)s2 * 8 + lane];
        float4 a3 = uin[(size_t)s3 * 8 + lane];
        float4 a4 = uin[(size_t)s4 * 8 + lane];
        float4 a5 = uin[(size_t)s5 * 8 + lane];
        float4 a6 = uin[(size_t)s6 * 8 + lane];
        float4 a7 = uin[(size_t)s7 * 8 + lane];
        if (FIRST) {
            float w0 = norm[s0], w1 = norm[s1], w2 = norm[s2], w3 = norm[s3];
            float w4 = norm[s4], w5 = norm[s5], w6 = norm[s6], w7 = norm[s7];
            acc.x += ((w0*a0.x + w1*a1.x) + (w2*a2.x + w3*a3.x)) +
                     ((w4*a4.x + w5*a5.x) + (w6*a6.x + w7*a7.x));
            acc.y += ((w0*a0.y + w1*a1.y) + (w2*a2.y + w3*a3.y)) +
                     ((w4*a4.y + w5*a5.y) + (w6*a6.y + w7*a7.y));
            acc.z += ((w0*a0.z + w1*a1.z) + (w2*a2.z + w3*a3.z)) +
                     ((w4*a4.z + w5*a5.z) + (w6*a6.z + w7*a7.z));
            acc.w += ((w0*a0.w + w1*a1.w) + (w2*a2.w + w3*a3.w)) +
                     ((w4*a4.w + w5*a5.w) + (w6*a6.w + w7*a7.w));
        } else {
            acc.x += ((a0.x + a1.x) + (a2.x + a3.x)) + ((a4.x + a5.x) + (a6.x + a7.x));
            acc.y += ((a0.y + a1.y) + (a2.y + a3.y)) + ((a4.y + a5.y) + (a6.y + a7.y));
            acc.z += ((a0.z + a1.z) + (a2.z + a3.z)) + ((a4.z + a5.z) + (a6.z + a7.z));
            acc.w += ((a0.w + a1.w) + (a2.w + a3.w)) + ((a4.w + a5.w) + (a6.w + a7.w));
        }
    }
    for (; e < re; ++e) {
        int s = col[e];
        float4 a = uin[(size_t)s * 8 + lane];
        float w = FIRST ? norm[s] : 1.0f;
        acc.x += w * a.x; acc.y += w * a.y;
        acc.z += w * a.z; acc.w += w * a.w;
    }
    float nn = norm[node];
    float w = LAST ? nn : nn * nn;
    acc.x *= w; acc.y *= w; acc.z *= w; acc.w *= w;
    if (LAST) {
        float4 bb = bias4[lane];
        acc.x += bb.x; acc.y += bb.y; acc.z += bb.z; acc.w += bb.w;
    }
    uout[(size_t)node * 8 + lane] = acc;
}

extern "C" void kernel_launch(void* const* d_in, const int* in_sizes, int n_in,
                              void* d_out, int out_size, void* d_ws, size_t ws_size,
                              hipStream_t stream) {
    const float* feat = (const float*)d_in[0];
    const int*   src  = (const int*)d_in[1];
    const int*   dst  = (const int*)d_in[2];
    const float* W    = (const float*)d_in[3];
    const float* b    = (const float*)d_in[4];
    float* out = (float*)d_out;

    char* ws = (char*)d_ws;
    size_t off = 0;
    auto alloc = [&](size_t bytes) {
        void* p = ws + off;
        off = (off + bytes + 255) & ~(size_t)255;
        return p;
    };
    float*    norm    = (float*)alloc((size_t)NNODES * 4);
    int2*     entries = (int2*)alloc((size_t)NBUCK * PB * 8);
    int*      gcur    = (int*)alloc((size_t)NBUCK * CUR_PAD * 4);
    unsigned* packed  = (unsigned*)alloc((size_t)NBUCK * PCAP * 4);
    int*      col     = (int*)alloc((size_t)NBUCK * PCAP * 4);
    float*    h0      = (float*)alloc((size_t)NNODES * OUTF * 4);
    float*    h1      = (float*)alloc((size_t)NNODES * OUTF * 4);

    // ---- init cursors, then fused {edge binning || projection} ----
    k_initcur<<<(NBUCK + 255) / 256, 256, 0, stream>>>(gcur);
    k_binproj<<<BIN_BLOCKS + PROJ_BLOCKS, 256, 0, stream>>>(
        (const int4*)src, (const int4*)dst, gcur, packed,
        (const float4*)feat, (const float4*)W, (float2*)h0);
    k_place<<<NBUCK, 256, 0, stream>>>(packed, gcur, col, entries, norm);

    // ---- 4 hops (hop1 applies norm[src]; u-space thereafter) ----
    const int ggrid = (NBUCK * PB * 8 + 255) / 256;
    k_gather<true,  false><<<ggrid, 256, 0, stream>>>(
        (const float4*)h0, (float4*)h1, entries, col, norm, nullptr);
    k_gather<false, false><<<ggrid, 256, 0, stream>>>(
        (const float4*)h1, (float4*)h0, entries, col, norm, nullptr);
    k_gather<false, false><<<ggrid, 256, 0, stream>>>(
        (const float4*)h0, (float4*)h1, entries, col, norm, nullptr);
    k_gather<false, true><<<ggrid, 256, 0, stream>>>(
        (const float4*)h1, (float4*)out, entries, col, norm, (const float4*)b);
}